// Round 15
// baseline (2323.863 us; speedup 1.0000x reference)
//
#include <hip/hip_runtime.h>
#include <hip/hip_bf16.h>

// Problem dims
#define V_ 50000
#define E_ 300
#define H_ 800
#define K_ 128
#define B_ 131072

typedef float  f32x4 __attribute__((ext_vector_type(4)));
typedef float  f32x2 __attribute__((ext_vector_type(2)));
typedef int    i32x4 __attribute__((ext_vector_type(4)));
typedef int    i32x8 __attribute__((ext_vector_type(8)));
typedef unsigned int u32x2 __attribute__((ext_vector_type(2)));
typedef unsigned int u32x4 __attribute__((ext_vector_type(4)));
typedef __bf16 bf16x8 __attribute__((ext_vector_type(8)));

#define LOG2E 1.4426950408889634f
#define HSTR 912   // LDS h stride bytes: 16B-aligned

// ---------------- ws layout (bytes) ----------------
static constexpr size_t OFF_ETB    = 0;                                  // bf16 [50048][128]
static constexpr size_t SZ_ETB     = (size_t)50048 * 128 * 2;            // 12,812,288
static constexpr size_t OFF_COLSUM = SZ_ETB;                             // 128 f32
static constexpr size_t OFF_PART   = OFF_COLSUM + 512;                   // [0]=loss,[1]=kld
static constexpr size_t OFF_Q1P8   = OFF_COLSUM + 1024;                  // 50 strips x 3 chunks x 2KB
static constexpr size_t OFF_Q2P8   = OFF_Q1P8 + (size_t)150 * 2048;      // 50 x 7 x 2KB
static constexpr size_t OFF_HEADP8 = OFF_Q2P8 + (size_t)350 * 2048;      // 16 x 7 x 2KB (mu 0-7, ls 8-15)
static constexpr size_t OFF_XP8    = OFF_HEADP8 + (size_t)112 * 2048;    // 8192 rfg x 3 chunks x 2KB

static __device__ __forceinline__ f32x4 mfma_bf16(i32x4 a, i32x4 b, f32x4 c) {
  return __builtin_amdgcn_mfma_f32_16x16x32_bf16(
      __builtin_bit_cast(bf16x8, a), __builtin_bit_cast(bf16x8, b), c, 0, 0, 0);
}
// MX-scaled fp8xfp8, K=128, all scales = 1.0 (E8M0 0x7F in every byte)
static __device__ __forceinline__ f32x4 mfma_mx(i32x8 a, i32x8 b, f32x4 c) {
  return __builtin_amdgcn_mfma_scale_f32_16x16x128_f8f6f4(
      a, b, c, 0 /*A=fp8*/, 0 /*B=fp8*/, 0, 0x7F7F7F7F, 0, 0x7F7F7F7F);
}

static __device__ __forceinline__ unsigned int cvt_pk_bf16(float a, float b) {
  unsigned int d;
  asm volatile("v_cvt_pk_bf16_f32 %0, %1, %2" : "=v"(d) : "v"(a), "v"(b));
  return d;
}
static __device__ __forceinline__ unsigned int pk_fp8x4(float a, float b, float c, float d) {
  int w = __builtin_amdgcn_cvt_pk_fp8_f32(a, b, 0, false);
  w = __builtin_amdgcn_cvt_pk_fp8_f32(c, d, w, true);
  return (unsigned int)w;
}

// tanh(x) = 1 - 2/(exp(2x)+1); correct limits at +/-inf without clamping.
static __device__ __forceinline__ float tanh_fast(float x) {
  float e = exp2f(x * 2.8853900817779268f);  // exp(2x)
  return __builtin_fmaf(-2.f, __builtin_amdgcn_rcpf(e + 1.f), 1.f);
}
static __device__ __forceinline__ float fast_log(float x) {
  return __builtin_amdgcn_logf(x) * 0.69314718056f;
}
static __device__ __forceinline__ float bf_lo(unsigned int w) {
  return __builtin_bit_cast(float, w << 16);
}
static __device__ __forceinline__ float bf_hi(unsigned int w) {
  return __builtin_bit_cast(float, w & 0xFFFF0000u);
}
static __device__ __forceinline__ f32x4 fzero() {
  f32x4 z; z.x = 0.f; z.y = 0.f; z.z = 0.f; z.w = 0.f; return z;
}
static __device__ __forceinline__ i32x8 ld32B(const void* p) {
  i32x4 a = *reinterpret_cast<const i32x4*>(p);
  i32x4 b = *reinterpret_cast<const i32x4*>(reinterpret_cast<const char*>(p) + 16);
  return __builtin_shufflevector(a, b, 0, 1, 2, 3, 4, 5, 6, 7);
}
static __device__ __forceinline__ unsigned int pk4tanh(f32x4 a, f32x4 b4) {
  return pk_fp8x4(tanh_fast(a[0] + b4.x), tanh_fast(a[1] + b4.y),
                  tanh_fast(a[2] + b4.z), tanh_fast(a[3] + b4.w));
}

// ---------------- pack units (64-lane jobs) ----------------
static __device__ __forceinline__ void pack_x_unit(int fi, int l, const float* __restrict__ X,
                                                   unsigned char* __restrict__ dst) {
  int rfg = fi / 3, c = fi - rfg * 3;
  int row = rfg * 16 + (l & 15);
  int k0 = c * 128 + ((l >> 4) << 5);
  const float* p = X + (size_t)row * 300 + k0;
  unsigned int o[8];
#pragma unroll
  for (int g = 0; g < 8; ++g) {
    f32x4 v = fzero();
    if (k0 + g * 4 < 300) v = *reinterpret_cast<const f32x4*>(p + g * 4);
    o[g] = pk_fp8x4(v.x, v.y, v.z, v.w);
  }
  *reinterpret_cast<u32x4*>(dst + (size_t)fi * 2048 + l * 32) = *reinterpret_cast<u32x4*>(&o[0]);
  *reinterpret_cast<u32x4*>(dst + (size_t)fi * 2048 + l * 32 + 16) = *reinterpret_cast<u32x4*>(&o[4]);
}
static __device__ __forceinline__ void pack_w_unit(int b, int l, const float* __restrict__ W,
                                                   int Kdim, int N, int nc,
                                                   unsigned char* __restrict__ dst) {
  int sl = b / nc, c = b - sl * nc;
  int n = sl * 16 + (l & 15);
  int k0 = c * 128 + ((l >> 4) << 5);
  unsigned int o[8];
#pragma unroll
  for (int r = 0; r < 8; ++r) {
    float t[4];
#pragma unroll
    for (int tt = 0; tt < 4; ++tt) {
      int k = k0 + r * 4 + tt;
      t[tt] = (k < Kdim) ? W[(size_t)k * N + n] : 0.f;
    }
    o[r] = pk_fp8x4(t[0], t[1], t[2], t[3]);
  }
  *reinterpret_cast<u32x4*>(dst + (size_t)b * 2048 + l * 32) = *reinterpret_cast<u32x4*>(&o[0]);
  *reinterpret_cast<u32x4*>(dst + (size_t)b * 2048 + l * 32 + 16) = *reinterpret_cast<u32x4*>(&o[4]);
}

#define NTB 782            // tb blocks (64 vocab rows each)
#define XU  (8192 * 3)     // x-frag units
#define NPACKU (XU + 612)  // + 150 q1 + 350 q2 + 56 mu + 56 ls

// ---------------- merged pre-kernel: tb (blocks 0..781) + all packing (rest) ----------------
__global__ __launch_bounds__(512) void pre_kernel(
    const float* __restrict__ rho, const float* __restrict__ alW,
    const float* __restrict__ biterms, const float* __restrict__ q1W,
    const float* __restrict__ q2W, const float* __restrict__ muW,
    const float* __restrict__ lsW,
    unsigned short* __restrict__ Etb, float* __restrict__ colsum,
    unsigned char* __restrict__ xp8, unsigned char* __restrict__ q1p8,
    unsigned char* __restrict__ q2p8, unsigned char* __restrict__ headp8) {
  const int tid = threadIdx.x;
  const int wid = tid >> 6, l = tid & 63;

  if (blockIdx.x >= NTB) {
    // ---- packing section ----
    int ub = (blockIdx.x - NTB) * 8 + wid;
    if (ub < XU) { pack_x_unit(ub, l, biterms, xp8); return; }
    int u2 = ub - XU;
    if (u2 < 150)      { pack_w_unit(u2, l, q1W, E_, H_, 3, q1p8); return; }
    else if (u2 < 500) { pack_w_unit(u2 - 150, l, q2W, H_, H_, 7, q2p8); return; }
    else if (u2 < 556) { pack_w_unit(u2 - 500, l, muW, H_, K_, 7, headp8); return; }
    else if (u2 < 612) { pack_w_unit(u2 - 556, l, lsW, H_, K_, 7, headp8 + (size_t)56 * 2048); return; }
    return;
  }

  // ---- tb section: Etb(bf16) = exp(rho @ alphas), colsum over vocab ----
  const int srow = l & 15, q = l >> 4;
  const int tile = blockIdx.x;
  const int acol = wid * 16 + srow;   // alpha column for this wave's strip

  // prefetch this wave's 10 alpha fragments inline; k>=300 zero-padded (makes rho
  // fast path safe: garbage k>=300 contributes 0)
  i32x4 awf[10];
#pragma unroll
  for (int ks = 0; ks < 9; ++ks) {
    float t[8];
#pragma unroll
    for (int j = 0; j < 8; ++j)
      t[j] = alW[(size_t)(ks * 32 + q * 8 + j) * K_ + acol];
    i32x4 o;
    o.x = (int)cvt_pk_bf16(t[0], t[1]);
    o.y = (int)cvt_pk_bf16(t[2], t[3]);
    o.z = (int)cvt_pk_bf16(t[4], t[5]);
    o.w = (int)cvt_pk_bf16(t[6], t[7]);
    awf[ks] = o;
  }
  {
    float t[8];
#pragma unroll
    for (int j = 0; j < 8; ++j) {
      int k = 288 + q * 8 + j;
      t[j] = (k < E_) ? alW[(size_t)k * K_ + acol] : 0.f;
    }
    i32x4 o;
    o.x = (int)cvt_pk_bf16(t[0], t[1]);
    o.y = (int)cvt_pk_bf16(t[2], t[3]);
    o.z = (int)cvt_pk_bf16(t[4], t[5]);
    o.w = (int)cvt_pk_bf16(t[6], t[7]);
    awf[9] = o;
  }

  f32x4 acc[4];
#pragma unroll
  for (int rf = 0; rf < 4; ++rf) acc[rf] = fzero();

  if (tile < NTB - 1) {
    // -------- fast path: no guards --------
    for (int ks = 0; ks < 10; ++ks) {
#pragma unroll
      for (int rf = 0; rf < 4; ++rf) {
        int row = tile * 64 + rf * 16 + srow;
        const float* p = rho + (size_t)row * 300 + ks * 32 + q * 8;
        f32x4 v0 = *reinterpret_cast<const f32x4*>(p);
        f32x4 v1 = *reinterpret_cast<const f32x4*>(p + 4);
        i32x4 rv;
        rv.x = (int)cvt_pk_bf16(v0.x, v0.y);
        rv.y = (int)cvt_pk_bf16(v0.z, v0.w);
        rv.z = (int)cvt_pk_bf16(v1.x, v1.y);
        rv.w = (int)cvt_pk_bf16(v1.z, v1.w);
        acc[rf] = mfma_bf16(awf[ks], rv, acc[rf]);
      }
    }
    float cs[4] = {0.f, 0.f, 0.f, 0.f};
#pragma unroll
    for (int rf = 0; rf < 4; ++rf) {
      int row = tile * 64 + rf * 16 + srow;
      float e0 = exp2f(acc[rf][0] * LOG2E);
      float e1 = exp2f(acc[rf][1] * LOG2E);
      float e2 = exp2f(acc[rf][2] * LOG2E);
      float e3 = exp2f(acc[rf][3] * LOG2E);
      u32x2 o;
      o.x = cvt_pk_bf16(e0, e1);
      o.y = cvt_pk_bf16(e2, e3);
      *reinterpret_cast<u32x2*>(Etb + (size_t)row * 128 + wid * 16 + q * 4) = o;
      cs[0] += e0; cs[1] += e1; cs[2] += e2; cs[3] += e3;
    }
#pragma unroll
    for (int d = 1; d < 16; d <<= 1) {
#pragma unroll
      for (int r = 0; r < 4; ++r) cs[r] += __shfl_xor(cs[r], d);
    }
    if (srow == 0) {
#pragma unroll
      for (int r = 0; r < 4; ++r) atomicAdd(&colsum[wid * 16 + q * 4 + r], cs[r]);
    }
    return;
  }

  // -------- guarded path (last tile only) --------
  for (int ks = 0; ks < 10; ++ks) {
#pragma unroll
    for (int rf = 0; rf < 4; ++rf) {
      int row = tile * 64 + rf * 16 + srow;
      f32x4 v0 = fzero(), v1 = fzero();
      if (row < V_) {
        const float* p = rho + (size_t)row * 300 + ks * 32 + q * 8;
        if (ks < 9) {
          v0 = *reinterpret_cast<const f32x4*>(p);
          v1 = *reinterpret_cast<const f32x4*>(p + 4);
        } else {
          if (q < 2)  v0 = *reinterpret_cast<const f32x4*>(p);
          if (q == 0) v1 = *reinterpret_cast<const f32x4*>(p + 4);
        }
      }
      i32x4 rv;
      rv.x = (int)cvt_pk_bf16(v0.x, v0.y);
      rv.y = (int)cvt_pk_bf16(v0.z, v0.w);
      rv.z = (int)cvt_pk_bf16(v1.x, v1.y);
      rv.w = (int)cvt_pk_bf16(v1.z, v1.w);
      acc[rf] = mfma_bf16(awf[ks], rv, acc[rf]);
    }
  }
  float cs[4] = {0.f, 0.f, 0.f, 0.f};
#pragma unroll
  for (int rf = 0; rf < 4; ++rf) {
    int row = tile * 64 + rf * 16 + srow;
    float e0 = exp2f(acc[rf][0] * LOG2E);
    float e1 = exp2f(acc[rf][1] * LOG2E);
    float e2 = exp2f(acc[rf][2] * LOG2E);
    float e3 = exp2f(acc[rf][3] * LOG2E);
    if (row < V_) {
      u32x2 o;
      o.x = cvt_pk_bf16(e0, e1);
      o.y = cvt_pk_bf16(e2, e3);
      *reinterpret_cast<u32x2*>(Etb + (size_t)row * 128 + wid * 16 + q * 4) = o;
      cs[0] += e0; cs[1] += e1; cs[2] += e2; cs[3] += e3;
    }
  }
#pragma unroll
  for (int d = 1; d < 16; d <<= 1) {
#pragma unroll
    for (int r = 0; r < 4; ++r) cs[r] += __shfl_xor(cs[r], d);
  }
  if (srow == 0) {
#pragma unroll
    for (int r = 0; r < 4; ++r) atomicAdd(&colsum[wid * 16 + q * 4 + r], cs[r]);
  }
}

// ---------- fused main kernel: 64 rows/block, 16 waves (1024 thr), <=3.25 strips/wave ----
// 1024 thr = 4 waves/SIMD -> launchability forces <=128 unified regs -> 16 waves/CU
// (+33% latency hiding vs r11's 12). This is the first 128-cap config whose hot live
// set FITS: acc 64 AGPR + w 32 + x/h 8-16 + addr ~15 = ~120-127. GEMM3: exactly 1
// head strip per wave. WRITE_SIZE = spill tripwire (if MB-scale -> revert to r14).
// NO s_setprio (r12), NO merged finalize fence (r13).
__global__ __launch_bounds__(1024) void fused_kernel(
    const int* __restrict__ bi_idx,
    const float* __restrict__ q1b, const float* __restrict__ q2b,
    const float* __restrict__ mub, const float* __restrict__ lsb,
    const unsigned char* __restrict__ xp8, const unsigned char* __restrict__ q1p8,
    const unsigned char* __restrict__ q2p8, const unsigned char* __restrict__ headp8,
    const unsigned short* __restrict__ Etb, const float* __restrict__ colsum,
    float* __restrict__ partial) {
  __shared__ __align__(16) unsigned char sH[64 * HSTR];   // 58,368 B (fp8 h1/h2, 896 cols)
  __shared__ __align__(16) unsigned char sMuB[64 * 256];  // 16,384 B (bf16 mu, XOR-swizzled)
  __shared__ __align__(16) float sInv[128];
  __shared__ float sRed[32];

  const int tid = threadIdx.x, wid = tid >> 6, l = tid & 63;
  const int swid = __builtin_amdgcn_readfirstlane(wid);   // 0..15
  const int srow = l & 15, q = l >> 4;
  const unsigned loff = (unsigned)l * 32u;
  const int row0 = blockIdx.x * 64;
  const bool has4 = (swid < 2);   // wave-uniform: strip swid+48 exists (48,49)

  if (tid < 128) { float c = colsum[tid]; sInv[tid] = 1.f / (c * c); }
  char* sHb = reinterpret_cast<char*>(sH);
  // zero-fill h cols 800..895: 64 rows x 24 dwords = 1536 dwords; threads 0..767 x2
  if (tid < 768) {
    int idx = tid * 2;
    int zr = idx / 24, zc = idx - zr * 24;
    u32x2 z2; z2.x = 0u; z2.y = 0u;
    *reinterpret_cast<u32x2*>(sHb + zr * HSTR + 800 + zc * 4) = z2;
  }

  f32x4 acc[4][4];   // [strip si][row-frag rf]

  // ---- GEMM1: h1 = tanh(x @ q1 + b1) -> sH fp8; strips s = swid + 16*si ----
#pragma unroll
  for (int si = 0; si < 4; ++si)
#pragma unroll
    for (int rf = 0; rf < 4; ++rf) acc[si][rf] = fzero();
#pragma unroll
  for (int c = 0; c < 3; ++c) {
    i32x8 w0 = ld32B(q1p8 + ((size_t)swid * 3 + c) * 2048 + loff);
    i32x8 w1 = ld32B(q1p8 + ((size_t)(swid + 16) * 3 + c) * 2048 + loff);
    i32x8 w2 = ld32B(q1p8 + ((size_t)(swid + 32) * 3 + c) * 2048 + loff);
    i32x8 w3 = w0;
    if (has4) w3 = ld32B(q1p8 + ((size_t)(swid + 48) * 3 + c) * 2048 + loff);
#pragma unroll
    for (int rf = 0; rf < 4; ++rf) {
      i32x8 x = ld32B(xp8 + ((size_t)(blockIdx.x * 4 + rf) * 3 + c) * 2048 + loff);
      acc[0][rf] = mfma_mx(w0, x, acc[0][rf]);
      acc[1][rf] = mfma_mx(w1, x, acc[1][rf]);
      acc[2][rf] = mfma_mx(w2, x, acc[2][rf]);
      if (has4) acc[3][rf] = mfma_mx(w3, x, acc[3][rf]);
    }
  }
#pragma unroll
  for (int si = 0; si < 4; ++si) {
    int s = swid + 16 * si;
    if (s < 50) {
      f32x4 b4 = *reinterpret_cast<const f32x4*>(q1b + s * 16 + q * 4);
#pragma unroll
      for (int rf = 0; rf < 4; ++rf)
        *reinterpret_cast<unsigned int*>(
            sHb + (rf * 16 + srow) * HSTR + s * 16 + q * 4) = pk4tanh(acc[si][rf], b4);
    }
  }
  __syncthreads();  // h1 complete

  // ---- GEMM2: h2 = tanh(h1 @ q2 + b2); single pass, all reads before one barrier ----
#pragma unroll
  for (int si = 0; si < 4; ++si)
#pragma unroll
    for (int rf = 0; rf < 4; ++rf) acc[si][rf] = fzero();
  for (int c = 0; c < 7; ++c) {
    i32x8 w0 = ld32B(q2p8 + ((size_t)swid * 7 + c) * 2048 + loff);
    i32x8 w1 = ld32B(q2p8 + ((size_t)(swid + 16) * 7 + c) * 2048 + loff);
    i32x8 w2 = ld32B(q2p8 + ((size_t)(swid + 32) * 7 + c) * 2048 + loff);
    i32x8 w3 = w0;
    if (has4) w3 = ld32B(q2p8 + ((size_t)(swid + 48) * 7 + c) * 2048 + loff);
#pragma unroll
    for (int rf = 0; rf < 4; ++rf) {
      i32x8 h = ld32B(sHb + (rf * 16 + srow) * HSTR + c * 128 + q * 32);
      acc[0][rf] = mfma_mx(w0, h, acc[0][rf]);
      acc[1][rf] = mfma_mx(w1, h, acc[1][rf]);
      acc[2][rf] = mfma_mx(w2, h, acc[2][rf]);
      if (has4) acc[3][rf] = mfma_mx(w3, h, acc[3][rf]);
    }
  }
  __syncthreads();  // ALL h1 reads complete -> safe to overwrite in place
#pragma unroll
  for (int si = 0; si < 4; ++si) {
    int s = swid + 16 * si;
    if (s < 50) {
      f32x4 b4 = *reinterpret_cast<const f32x4*>(q2b + s * 16 + q * 4);
#pragma unroll
      for (int rf = 0; rf < 4; ++rf)
        *reinterpret_cast<unsigned int*>(
            sHb + (rf * 16 + srow) * HSTR + s * 16 + q * 4) = pk4tanh(acc[si][rf], b4);
    }
  }
  __syncthreads();  // h2 complete

  // ---- GEMM3: head strip s = swid exactly (0-7: mu, 8-15: ls); kld; mu->sMuB ----
  f32x4 acc3[4];
#pragma unroll
  for (int rf = 0; rf < 4; ++rf) acc3[rf] = fzero();
  for (int c = 0; c < 7; ++c) {
    i32x8 w = ld32B(headp8 + ((size_t)swid * 7 + c) * 2048 + loff);
#pragma unroll
    for (int rf = 0; rf < 4; ++rf) {
      i32x8 a8 = ld32B(sHb + (rf * 16 + srow) * HSTR + c * 128 + q * 32);
      acc3[rf] = mfma_mx(w, a8, acc3[rf]);
    }
  }
  {
    float kldp = 0.f;
    if (swid < 8) {          // mu strip swid
      f32x4 mb4 = *reinterpret_cast<const f32x4*>(mub + swid * 16 + q * 4);
      unsigned coff = ((unsigned)(swid * 32 + q * 8)) ^ (((unsigned)(srow & 7)) << 5);
#pragma unroll
      for (int rf = 0; rf < 4; ++rf) {
        float m0 = acc3[rf][0] + mb4.x, m1 = acc3[rf][1] + mb4.y;
        float m2 = acc3[rf][2] + mb4.z, m3 = acc3[rf][3] + mb4.w;
        kldp -= m0 * m0 + m1 * m1 + m2 * m2 + m3 * m3;
        u32x2 o;
        o.x = cvt_pk_bf16(m0, m1);
        o.y = cvt_pk_bf16(m2, m3);
        *reinterpret_cast<u32x2*>(sMuB + (rf * 16 + srow) * 256 + coff) = o;
      }
    } else {                 // ls strip swid-8
      f32x4 lb4 = *reinterpret_cast<const f32x4*>(lsb + (swid - 8) * 16 + q * 4);
#pragma unroll
      for (int rf = 0; rf < 4; ++rf) {
        float v0 = acc3[rf][0] + lb4.x, v1 = acc3[rf][1] + lb4.y;
        float v2 = acc3[rf][2] + lb4.z, v3 = acc3[rf][3] + lb4.w;
        kldp += 4.f + v0 + v1 + v2 + v3
              - exp2f(v0 * LOG2E) - exp2f(v1 * LOG2E)
              - exp2f(v2 * LOG2E) - exp2f(v3 * LOG2E);
      }
    }
#pragma unroll
    for (int d = 1; d < 64; d <<= 1) kldp += __shfl_xor(kldp, d);
    if (l == 0) sRed[wid] = kldp;
  }
  __syncthreads();

  // ---- decode (all 16 waves, 4 rows each): lane = (row rg=l>>4, topic-group tg=l&15
  //      of 8 topics) ----
  {
    const int rg = l >> 4, tg = l & 15;
    const int dr = wid * 4 + rg;   // 0..63
    int2 bi = reinterpret_cast<const int2*>(bi_idx)[row0 + dr];
    const char* EtbB = reinterpret_cast<const char*>(Etb);
    u32x4 e0 = *reinterpret_cast<const u32x4*>(EtbB + (size_t)bi.x * 256 + tg * 16);
    u32x4 e1 = *reinterpret_cast<const u32x4*>(EtbB + (size_t)bi.y * 256 + tg * 16);
    unsigned moff = ((unsigned)(tg * 16)) ^ (((unsigned)(dr & 7)) << 5);
    u32x4 mw4 = *reinterpret_cast<const u32x4*>(
        reinterpret_cast<const char*>(sMuB) + dr * 256 + moff);
    f32x4 iva = *reinterpret_cast<const f32x4*>(sInv + tg * 8);
    f32x4 ivb = *reinterpret_cast<const f32x4*>(sInv + tg * 8 + 4);
    float ivf[8] = {iva.x, iva.y, iva.z, iva.w, ivb.x, ivb.y, ivb.z, ivb.w};
    unsigned mw[4]  = {mw4.x, mw4.y, mw4.z, mw4.w};
    unsigned ew0[4] = {e0.x, e0.y, e0.z, e0.w};
    unsigned ew1[4] = {e1.x, e1.y, e1.z, e1.w};
    float den = 0.f, pacc = 0.f;
#pragma unroll
    for (int i = 0; i < 4; ++i) {
      float ta = exp2f(bf_lo(mw[i]) * LOG2E);
      float tb = exp2f(bf_hi(mw[i]) * LOG2E);
      den += ta + tb;
      float ea = bf_lo(ew0[i]) * bf_lo(ew1[i]);
      float eb = bf_hi(ew0[i]) * bf_hi(ew1[i]);
      pacc += ta * ta * ea * ivf[2 * i] + tb * tb * eb * ivf[2 * i + 1];
    }
    den  += __shfl_xor(den, 1);  pacc += __shfl_xor(pacc, 1);
    den  += __shfl_xor(den, 2);  pacc += __shfl_xor(pacc, 2);
    den  += __shfl_xor(den, 4);  pacc += __shfl_xor(pacc, 4);
    den  += __shfl_xor(den, 8);  pacc += __shfl_xor(pacc, 8);
    float lr = 0.f;
    if (tg == 0)
      lr = fast_log(pacc * __builtin_amdgcn_rcpf(den * den) + 1e-6f);
    lr += __shfl_xor(lr, 16);
    lr += __shfl_xor(lr, 32);
    if (l == 0) sRed[16 + wid] = lr;
  }
  __syncthreads();
  if (tid == 0) {
    float k = 0.f, s = 0.f;
#pragma unroll
    for (int i = 0; i < 16; ++i) { k += sRed[i]; s += sRed[16 + i]; }
    atomicAdd(&partial[1], k);
    atomicAdd(&partial[0], s);
  }
}

__global__ void finalize_kernel(const float* __restrict__ partial, float* __restrict__ out) {
  if (threadIdx.x == 0) {
    out[0] = partial[0] / (float)B_;
    out[1] = -0.5f * partial[1] / (float)B_;
  }
}

extern "C" void kernel_launch(void* const* d_in, const int* in_sizes, int n_in,
                              void* d_out, int out_size, void* d_ws, size_t ws_size,
                              hipStream_t stream) {
  const int*   bi_idx   = (const int*)d_in[0];
  const float* biterms  = (const float*)d_in[1];
  const float* rho      = (const float*)d_in[2];
  const float* alphas_W = (const float*)d_in[3];
  const float* q1_W     = (const float*)d_in[4];
  const float* q1_b     = (const float*)d_in[5];
  const float* q2_W     = (const float*)d_in[6];
  const float* q2_b     = (const float*)d_in[7];
  const float* mu_W     = (const float*)d_in[8];
  const float* mu_b     = (const float*)d_in[9];
  const float* ls_W     = (const float*)d_in[10];
  const float* ls_b     = (const float*)d_in[11];

  char* ws = (char*)d_ws;
  unsigned short* Etb   = (unsigned short*)(ws + OFF_ETB);
  float* colsum  = (float*)(ws + OFF_COLSUM);
  float* partial = (float*)(ws + OFF_PART);
  unsigned char*  q1p8  = (unsigned char*)(ws + OFF_Q1P8);
  unsigned char*  q2p8  = (unsigned char*)(ws + OFF_Q2P8);
  unsigned char*  headp8= (unsigned char*)(ws + OFF_HEADP8);
  unsigned char*  xp8   = (unsigned char*)(ws + OFF_XP8);

  hipMemsetAsync(ws + OFF_COLSUM, 0, 1024, stream);  // colsum + partials (must precede pre_kernel atomics)

  // merged pre-kernel: 782 tb blocks + ceil(25188/8)=3149 pack blocks
  pre_kernel<<<NTB + (NPACKU + 7) / 8, 512, 0, stream>>>(
      rho, alphas_W, biterms, q1_W, q2_W, mu_W, ls_W,
      Etb, colsum, xp8, q1p8, q2p8, headp8);

  fused_kernel<<<B_ / 64, 1024, 0, stream>>>(bi_idx, q1_b, q2_b, mu_b, ls_b,
                                             xp8, q1p8, q2p8, headp8, Etb, colsum, partial);

  finalize_kernel<<<1, 64, 0, stream>>>(partial, (float*)d_out);
}

// Round 16
// 405.972 us; speedup vs baseline: 5.7242x; 5.7242x over previous
//
#include <hip/hip_runtime.h>
#include <hip/hip_bf16.h>

// Problem dims
#define V_ 50000
#define E_ 300
#define H_ 800
#define K_ 128
#define B_ 131072

typedef float  f32x4 __attribute__((ext_vector_type(4)));
typedef float  f32x2 __attribute__((ext_vector_type(2)));
typedef int    i32x4 __attribute__((ext_vector_type(4)));
typedef int    i32x8 __attribute__((ext_vector_type(8)));
typedef unsigned int u32x2 __attribute__((ext_vector_type(2)));
typedef unsigned int u32x4 __attribute__((ext_vector_type(4)));
typedef __bf16 bf16x8 __attribute__((ext_vector_type(8)));

#define LOG2E 1.4426950408889634f
#define HSTR 912   // LDS h stride bytes: 16B-aligned

// ---------------- ws layout (bytes) ----------------
static constexpr size_t OFF_ETB    = 0;                                  // bf16 [50048][128]
static constexpr size_t SZ_ETB     = (size_t)50048 * 128 * 2;            // 12,812,288
static constexpr size_t OFF_COLSUM = SZ_ETB;                             // 128 f32
static constexpr size_t OFF_PART   = OFF_COLSUM + 512;                   // [0]=loss,[1]=kld
static constexpr size_t OFF_Q1P8   = OFF_COLSUM + 1024;                  // 50 strips x 3 chunks x 2KB
static constexpr size_t OFF_Q2P8   = OFF_Q1P8 + (size_t)150 * 2048;      // 50 x 7 x 2KB
static constexpr size_t OFF_HEADP8 = OFF_Q2P8 + (size_t)350 * 2048;      // 16 x 7 x 2KB (mu 0-7, ls 8-15)
static constexpr size_t OFF_XP8    = OFF_HEADP8 + (size_t)112 * 2048;    // 8192 rfg x 3 chunks x 2KB

static __device__ __forceinline__ f32x4 mfma_bf16(i32x4 a, i32x4 b, f32x4 c) {
  return __builtin_amdgcn_mfma_f32_16x16x32_bf16(
      __builtin_bit_cast(bf16x8, a), __builtin_bit_cast(bf16x8, b), c, 0, 0, 0);
}
// MX-scaled fp8xfp8, K=128, all scales = 1.0 (E8M0 0x7F in every byte)
static __device__ __forceinline__ f32x4 mfma_mx(i32x8 a, i32x8 b, f32x4 c) {
  return __builtin_amdgcn_mfma_scale_f32_16x16x128_f8f6f4(
      a, b, c, 0 /*A=fp8*/, 0 /*B=fp8*/, 0, 0x7F7F7F7F, 0, 0x7F7F7F7F);
}

static __device__ __forceinline__ unsigned int cvt_pk_bf16(float a, float b) {
  unsigned int d;
  asm volatile("v_cvt_pk_bf16_f32 %0, %1, %2" : "=v"(d) : "v"(a), "v"(b));
  return d;
}
static __device__ __forceinline__ unsigned int pk_fp8x4(float a, float b, float c, float d) {
  int w = __builtin_amdgcn_cvt_pk_fp8_f32(a, b, 0, false);
  w = __builtin_amdgcn_cvt_pk_fp8_f32(c, d, w, true);
  return (unsigned int)w;
}

// tanh(x) = 1 - 2/(exp(2x)+1); correct limits at +/-inf without clamping.
static __device__ __forceinline__ float tanh_fast(float x) {
  float e = exp2f(x * 2.8853900817779268f);  // exp(2x)
  return __builtin_fmaf(-2.f, __builtin_amdgcn_rcpf(e + 1.f), 1.f);
}
static __device__ __forceinline__ float fast_log(float x) {
  return __builtin_amdgcn_logf(x) * 0.69314718056f;
}
static __device__ __forceinline__ float bf_lo(unsigned int w) {
  return __builtin_bit_cast(float, w << 16);
}
static __device__ __forceinline__ float bf_hi(unsigned int w) {
  return __builtin_bit_cast(float, w & 0xFFFF0000u);
}
static __device__ __forceinline__ f32x4 fzero() {
  f32x4 z; z.x = 0.f; z.y = 0.f; z.z = 0.f; z.w = 0.f; return z;
}
static __device__ __forceinline__ i32x8 ld32B(const void* p) {
  i32x4 a = *reinterpret_cast<const i32x4*>(p);
  i32x4 b = *reinterpret_cast<const i32x4*>(reinterpret_cast<const char*>(p) + 16);
  return __builtin_shufflevector(a, b, 0, 1, 2, 3, 4, 5, 6, 7);
}
static __device__ __forceinline__ unsigned int pk4tanh(f32x4 a, f32x4 b4) {
  return pk_fp8x4(tanh_fast(a[0] + b4.x), tanh_fast(a[1] + b4.y),
                  tanh_fast(a[2] + b4.z), tanh_fast(a[3] + b4.w));
}

// ---------------- pack units (64-lane jobs) ----------------
static __device__ __forceinline__ void pack_x_unit(int fi, int l, const float* __restrict__ X,
                                                   unsigned char* __restrict__ dst) {
  int rfg = fi / 3, c = fi - rfg * 3;
  int row = rfg * 16 + (l & 15);
  int k0 = c * 128 + ((l >> 4) << 5);
  const float* p = X + (size_t)row * 300 + k0;
  unsigned int o[8];
  if (c < 2) {
    // fast path: k0+28 <= 252 < 300 always -> unguarded
#pragma unroll
    for (int g = 0; g < 8; ++g) {
      f32x4 v = *reinterpret_cast<const f32x4*>(p + g * 4);
      o[g] = pk_fp8x4(v.x, v.y, v.z, v.w);
    }
  } else {
#pragma unroll
    for (int g = 0; g < 8; ++g) {
      f32x4 v = fzero();
      if (k0 + g * 4 < 300) v = *reinterpret_cast<const f32x4*>(p + g * 4);
      o[g] = pk_fp8x4(v.x, v.y, v.z, v.w);
    }
  }
  *reinterpret_cast<u32x4*>(dst + (size_t)fi * 2048 + l * 32) = *reinterpret_cast<u32x4*>(&o[0]);
  *reinterpret_cast<u32x4*>(dst + (size_t)fi * 2048 + l * 32 + 16) = *reinterpret_cast<u32x4*>(&o[4]);
}
static __device__ __forceinline__ void pack_w_unit(int b, int l, const float* __restrict__ W,
                                                   int Kdim, int N, int nc,
                                                   unsigned char* __restrict__ dst) {
  int sl = b / nc, c = b - sl * nc;
  int n = sl * 16 + (l & 15);
  int k0 = c * 128 + ((l >> 4) << 5);
  unsigned int o[8];
#pragma unroll
  for (int r = 0; r < 8; ++r) {
    float t[4];
#pragma unroll
    for (int tt = 0; tt < 4; ++tt) {
      int k = k0 + r * 4 + tt;
      t[tt] = (k < Kdim) ? W[(size_t)k * N + n] : 0.f;
    }
    o[r] = pk_fp8x4(t[0], t[1], t[2], t[3]);
  }
  *reinterpret_cast<u32x4*>(dst + (size_t)b * 2048 + l * 32) = *reinterpret_cast<u32x4*>(&o[0]);
  *reinterpret_cast<u32x4*>(dst + (size_t)b * 2048 + l * 32 + 16) = *reinterpret_cast<u32x4*>(&o[4]);
}

#define NTB 782            // tb blocks (64 vocab rows each)
#define XU  (8192 * 3)     // x-frag units
#define NPACKU (XU + 612)  // + 150 q1 + 350 q2 + 56 mu + 56 ls

// ---------------- merged pre-kernel: tb (blocks 0..781) + all packing (rest) ----------------
__global__ __launch_bounds__(512) void pre_kernel(
    const float* __restrict__ rho, const float* __restrict__ alW,
    const float* __restrict__ biterms, const float* __restrict__ q1W,
    const float* __restrict__ q2W, const float* __restrict__ muW,
    const float* __restrict__ lsW,
    unsigned short* __restrict__ Etb, float* __restrict__ colsum,
    unsigned char* __restrict__ xp8, unsigned char* __restrict__ q1p8,
    unsigned char* __restrict__ q2p8, unsigned char* __restrict__ headp8) {
  const int tid = threadIdx.x;
  const int wid = tid >> 6, l = tid & 63;

  if (blockIdx.x >= NTB) {
    // ---- packing section ----
    int ub = (blockIdx.x - NTB) * 8 + wid;
    if (ub < XU) { pack_x_unit(ub, l, biterms, xp8); return; }
    int u2 = ub - XU;
    if (u2 < 150)      { pack_w_unit(u2, l, q1W, E_, H_, 3, q1p8); return; }
    else if (u2 < 500) { pack_w_unit(u2 - 150, l, q2W, H_, H_, 7, q2p8); return; }
    else if (u2 < 556) { pack_w_unit(u2 - 500, l, muW, H_, K_, 7, headp8); return; }
    else if (u2 < 612) { pack_w_unit(u2 - 556, l, lsW, H_, K_, 7, headp8 + (size_t)56 * 2048); return; }
    return;
  }

  // ---- tb section: Etb(bf16) = exp(rho @ alphas), colsum over vocab ----
  const int srow = l & 15, q = l >> 4;
  const int tile = blockIdx.x;
  const int acol = wid * 16 + srow;   // alpha column for this wave's strip

  // prefetch this wave's 10 alpha fragments inline; k>=300 zero-padded (makes rho
  // fast path safe: garbage k>=300 contributes 0)
  i32x4 awf[10];
#pragma unroll
  for (int ks = 0; ks < 9; ++ks) {
    float t[8];
#pragma unroll
    for (int j = 0; j < 8; ++j)
      t[j] = alW[(size_t)(ks * 32 + q * 8 + j) * K_ + acol];
    i32x4 o;
    o.x = (int)cvt_pk_bf16(t[0], t[1]);
    o.y = (int)cvt_pk_bf16(t[2], t[3]);
    o.z = (int)cvt_pk_bf16(t[4], t[5]);
    o.w = (int)cvt_pk_bf16(t[6], t[7]);
    awf[ks] = o;
  }
  {
    float t[8];
#pragma unroll
    for (int j = 0; j < 8; ++j) {
      int k = 288 + q * 8 + j;
      t[j] = (k < E_) ? alW[(size_t)k * K_ + acol] : 0.f;
    }
    i32x4 o;
    o.x = (int)cvt_pk_bf16(t[0], t[1]);
    o.y = (int)cvt_pk_bf16(t[2], t[3]);
    o.z = (int)cvt_pk_bf16(t[4], t[5]);
    o.w = (int)cvt_pk_bf16(t[6], t[7]);
    awf[9] = o;
  }

  f32x4 acc[4];
#pragma unroll
  for (int rf = 0; rf < 4; ++rf) acc[rf] = fzero();

  if (tile < NTB - 1) {
    // -------- fast path: no guards --------
    for (int ks = 0; ks < 10; ++ks) {
#pragma unroll
      for (int rf = 0; rf < 4; ++rf) {
        int row = tile * 64 + rf * 16 + srow;
        const float* p = rho + (size_t)row * 300 + ks * 32 + q * 8;
        f32x4 v0 = *reinterpret_cast<const f32x4*>(p);
        f32x4 v1 = *reinterpret_cast<const f32x4*>(p + 4);
        i32x4 rv;
        rv.x = (int)cvt_pk_bf16(v0.x, v0.y);
        rv.y = (int)cvt_pk_bf16(v0.z, v0.w);
        rv.z = (int)cvt_pk_bf16(v1.x, v1.y);
        rv.w = (int)cvt_pk_bf16(v1.z, v1.w);
        acc[rf] = mfma_bf16(awf[ks], rv, acc[rf]);
      }
    }
    float cs[4] = {0.f, 0.f, 0.f, 0.f};
#pragma unroll
    for (int rf = 0; rf < 4; ++rf) {
      int row = tile * 64 + rf * 16 + srow;
      float e0 = exp2f(acc[rf][0] * LOG2E);
      float e1 = exp2f(acc[rf][1] * LOG2E);
      float e2 = exp2f(acc[rf][2] * LOG2E);
      float e3 = exp2f(acc[rf][3] * LOG2E);
      u32x2 o;
      o.x = cvt_pk_bf16(e0, e1);
      o.y = cvt_pk_bf16(e2, e3);
      *reinterpret_cast<u32x2*>(Etb + (size_t)row * 128 + wid * 16 + q * 4) = o;
      cs[0] += e0; cs[1] += e1; cs[2] += e2; cs[3] += e3;
    }
#pragma unroll
    for (int d = 1; d < 16; d <<= 1) {
#pragma unroll
      for (int r = 0; r < 4; ++r) cs[r] += __shfl_xor(cs[r], d);
    }
    if (srow == 0) {
#pragma unroll
      for (int r = 0; r < 4; ++r) atomicAdd(&colsum[wid * 16 + q * 4 + r], cs[r]);
    }
    return;
  }

  // -------- guarded path (last tile only) --------
  for (int ks = 0; ks < 10; ++ks) {
#pragma unroll
    for (int rf = 0; rf < 4; ++rf) {
      int row = tile * 64 + rf * 16 + srow;
      f32x4 v0 = fzero(), v1 = fzero();
      if (row < V_) {
        const float* p = rho + (size_t)row * 300 + ks * 32 + q * 8;
        if (ks < 9) {
          v0 = *reinterpret_cast<const f32x4*>(p);
          v1 = *reinterpret_cast<const f32x4*>(p + 4);
        } else {
          if (q < 2)  v0 = *reinterpret_cast<const f32x4*>(p);
          if (q == 0) v1 = *reinterpret_cast<const f32x4*>(p + 4);
        }
      }
      i32x4 rv;
      rv.x = (int)cvt_pk_bf16(v0.x, v0.y);
      rv.y = (int)cvt_pk_bf16(v0.z, v0.w);
      rv.z = (int)cvt_pk_bf16(v1.x, v1.y);
      rv.w = (int)cvt_pk_bf16(v1.z, v1.w);
      acc[rf] = mfma_bf16(awf[ks], rv, acc[rf]);
    }
  }
  float cs[4] = {0.f, 0.f, 0.f, 0.f};
#pragma unroll
  for (int rf = 0; rf < 4; ++rf) {
    int row = tile * 64 + rf * 16 + srow;
    float e0 = exp2f(acc[rf][0] * LOG2E);
    float e1 = exp2f(acc[rf][1] * LOG2E);
    float e2 = exp2f(acc[rf][2] * LOG2E);
    float e3 = exp2f(acc[rf][3] * LOG2E);
    if (row < V_) {
      u32x2 o;
      o.x = cvt_pk_bf16(e0, e1);
      o.y = cvt_pk_bf16(e2, e3);
      *reinterpret_cast<u32x2*>(Etb + (size_t)row * 128 + wid * 16 + q * 4) = o;
      cs[0] += e0; cs[1] += e1; cs[2] += e2; cs[3] += e3;
    }
  }
#pragma unroll
  for (int d = 1; d < 16; d <<= 1) {
#pragma unroll
    for (int r = 0; r < 4; ++r) cs[r] += __shfl_xor(cs[r], d);
  }
  if (srow == 0) {
#pragma unroll
    for (int r = 0; r < 4; ++r) atomicAdd(&colsum[wid * 16 + q * 4 + r], cs[r]);
  }
}

// ---------- fused main kernel: 64 rows/block, 12 waves (768 thr), 5 strips/wave ----------
// (768,3): 3 waves/SIMD, 170-reg cap; r11/r14 measured 72 arch + 80 AGPR = 152, no spill.
// r16 change: #pragma unroll on GEMM2/GEMM3 c-loops (GEMM1 already unrolled) so the
// scheduler can hoist c+1 loads above c's MFMAs (cross-iteration pipelining).
// Ledger: NO s_setprio (r12, -29us), NO merged-finalize fence (r13, -27us),
// NEVER the 128-reg cap (r2/r6/r15 all spilled; WRITE_SIZE = tripwire).
__global__ __launch_bounds__(768, 3) void fused_kernel(
    const int* __restrict__ bi_idx,
    const float* __restrict__ q1b, const float* __restrict__ q2b,
    const float* __restrict__ mub, const float* __restrict__ lsb,
    const unsigned char* __restrict__ xp8, const unsigned char* __restrict__ q1p8,
    const unsigned char* __restrict__ q2p8, const unsigned char* __restrict__ headp8,
    const unsigned short* __restrict__ Etb, const float* __restrict__ colsum,
    float* __restrict__ partial) {
  __shared__ __align__(16) unsigned char sH[64 * HSTR];   // 58,368 B (fp8 h1/h2, 896 cols)
  __shared__ __align__(16) unsigned char sMuB[64 * 256];  // 16,384 B (bf16 mu, XOR-swizzled)
  __shared__ __align__(16) float sInv[128];
  __shared__ float sRed[20];

  const int tid = threadIdx.x, wid = tid >> 6, l = tid & 63;
  const int swid = __builtin_amdgcn_readfirstlane(wid);   // 0..11
  const int srow = l & 15, q = l >> 4;
  const unsigned loff = (unsigned)l * 32u;
  const int row0 = blockIdx.x * 64;

  if (tid < 128) { float c = colsum[tid]; sInv[tid] = 1.f / (c * c); }
  char* sHb = reinterpret_cast<char*>(sH);
  // zero-fill h cols 800..895: 64 rows x 24 dwords = 1536 dwords / 768 thr = 2 each
  {
    int idx = tid * 2;
    int zr = idx / 24, zc = idx - zr * 24;
    u32x2 z2; z2.x = 0u; z2.y = 0u;
    *reinterpret_cast<u32x2*>(sHb + zr * HSTR + 800 + zc * 4) = z2;
  }

  f32x4 acc[5][4];

  // ---- GEMM1: h1 = tanh(x @ q1 + b1) -> sH fp8; strips s = swid + 12*si ----
#pragma unroll
  for (int si = 0; si < 5; ++si)
#pragma unroll
    for (int rf = 0; rf < 4; ++rf) acc[si][rf] = fzero();
#pragma unroll
  for (int c = 0; c < 3; ++c) {
    i32x8 x[4];
#pragma unroll
    for (int rf = 0; rf < 4; ++rf)
      x[rf] = ld32B(xp8 + ((size_t)(blockIdx.x * 4 + rf) * 3 + c) * 2048 + loff);
#pragma unroll
    for (int si = 0; si < 5; ++si) {
      int s = swid + 12 * si;
      if (s < 50) {
        i32x8 w = ld32B(q1p8 + ((size_t)s * 3 + c) * 2048 + loff);
#pragma unroll
        for (int rf = 0; rf < 4; ++rf) acc[si][rf] = mfma_mx(w, x[rf], acc[si][rf]);
      }
    }
  }
#pragma unroll
  for (int si = 0; si < 5; ++si) {
    int s = swid + 12 * si;
    if (s < 50) {
      f32x4 b4 = *reinterpret_cast<const f32x4*>(q1b + s * 16 + q * 4);
#pragma unroll
      for (int rf = 0; rf < 4; ++rf)
        *reinterpret_cast<unsigned int*>(
            sHb + (rf * 16 + srow) * HSTR + s * 16 + q * 4) = pk4tanh(acc[si][rf], b4);
    }
  }
  __syncthreads();  // h1 complete

  // ---- GEMM2: h2 = tanh(h1 @ q2 + b2); single pass, all reads before one barrier ----
#pragma unroll
  for (int si = 0; si < 5; ++si)
#pragma unroll
    for (int rf = 0; rf < 4; ++rf) acc[si][rf] = fzero();
#pragma unroll
  for (int c = 0; c < 7; ++c) {
    i32x8 h[4];
#pragma unroll
    for (int rf = 0; rf < 4; ++rf)
      h[rf] = ld32B(sHb + (rf * 16 + srow) * HSTR + c * 128 + q * 32);
#pragma unroll
    for (int si = 0; si < 5; ++si) {
      int s = swid + 12 * si;
      if (s < 50) {
        i32x8 w = ld32B(q2p8 + ((size_t)s * 7 + c) * 2048 + loff);
#pragma unroll
        for (int rf = 0; rf < 4; ++rf) acc[si][rf] = mfma_mx(w, h[rf], acc[si][rf]);
      }
    }
  }
  __syncthreads();  // ALL h1 reads complete -> safe to overwrite in place
#pragma unroll
  for (int si = 0; si < 5; ++si) {
    int s = swid + 12 * si;
    if (s < 50) {
      f32x4 b4 = *reinterpret_cast<const f32x4*>(q2b + s * 16 + q * 4);
#pragma unroll
      for (int rf = 0; rf < 4; ++rf)
        *reinterpret_cast<unsigned int*>(
            sHb + (rf * 16 + srow) * HSTR + s * 16 + q * 4) = pk4tanh(acc[si][rf], b4);
    }
  }
  __syncthreads();  // h2 complete

  // ---- GEMM3: head strips s = swid + 12*j, j=0..1 (s<8: mu, 8..15: ls); kld; mu->sMuB ----
  f32x4 acc3[2][4];
#pragma unroll
  for (int j = 0; j < 2; ++j)
#pragma unroll
    for (int rf = 0; rf < 4; ++rf) acc3[j][rf] = fzero();
#pragma unroll
  for (int c = 0; c < 7; ++c) {
    i32x8 a8[4];
#pragma unroll
    for (int rf = 0; rf < 4; ++rf)
      a8[rf] = ld32B(sHb + (rf * 16 + srow) * HSTR + c * 128 + q * 32);
#pragma unroll
    for (int j = 0; j < 2; ++j) {
      int s = swid + 12 * j;
      if (s < 16) {
        i32x8 w = ld32B(headp8 + ((size_t)s * 7 + c) * 2048 + loff);
#pragma unroll
        for (int rf = 0; rf < 4; ++rf) acc3[j][rf] = mfma_mx(w, a8[rf], acc3[j][rf]);
      }
    }
  }
  {
    float kldp = 0.f;
    unsigned swz = ((unsigned)(srow & 7)) << 5;
#pragma unroll
    for (int j = 0; j < 2; ++j) {
      int s = swid + 12 * j;
      if (s < 8) {            // mu strip s
        f32x4 mb4 = *reinterpret_cast<const f32x4*>(mub + s * 16 + q * 4);
        unsigned coff = ((unsigned)(s * 32 + q * 8)) ^ swz;
#pragma unroll
        for (int rf = 0; rf < 4; ++rf) {
          float m0 = acc3[j][rf][0] + mb4.x, m1 = acc3[j][rf][1] + mb4.y;
          float m2 = acc3[j][rf][2] + mb4.z, m3 = acc3[j][rf][3] + mb4.w;
          kldp -= m0 * m0 + m1 * m1 + m2 * m2 + m3 * m3;
          u32x2 o;
          o.x = cvt_pk_bf16(m0, m1);
          o.y = cvt_pk_bf16(m2, m3);
          *reinterpret_cast<u32x2*>(sMuB + (rf * 16 + srow) * 256 + coff) = o;
        }
      } else if (s < 16) {    // ls strip s-8
        f32x4 lb4 = *reinterpret_cast<const f32x4*>(lsb + (s - 8) * 16 + q * 4);
#pragma unroll
        for (int rf = 0; rf < 4; ++rf) {
          float v0 = acc3[j][rf][0] + lb4.x, v1 = acc3[j][rf][1] + lb4.y;
          float v2 = acc3[j][rf][2] + lb4.z, v3 = acc3[j][rf][3] + lb4.w;
          kldp += 4.f + v0 + v1 + v2 + v3
                - exp2f(v0 * LOG2E) - exp2f(v1 * LOG2E)
                - exp2f(v2 * LOG2E) - exp2f(v3 * LOG2E);
        }
      }
    }
#pragma unroll
    for (int d = 1; d < 64; d <<= 1) kldp += __shfl_xor(kldp, d);
    if (l == 0) sRed[wid] = kldp;
  }
  __syncthreads();

  // ---- decode (waves 0-7): lane = (row rg=l>>3, topic-group tg=l&7 of 16 topics) ----
  if (swid < 8) {
    const int rg = l >> 3, tg = l & 7;
    const int dr = wid * 8 + rg;   // 0..63
    int2 bi = reinterpret_cast<const int2*>(bi_idx)[row0 + dr];
    const char* EtbB = reinterpret_cast<const char*>(Etb);
    u32x4 e0a = *reinterpret_cast<const u32x4*>(EtbB + (size_t)bi.x * 256 + tg * 32);
    u32x4 e0b = *reinterpret_cast<const u32x4*>(EtbB + (size_t)bi.x * 256 + tg * 32 + 16);
    u32x4 e1a = *reinterpret_cast<const u32x4*>(EtbB + (size_t)bi.y * 256 + tg * 32);
    u32x4 e1b = *reinterpret_cast<const u32x4*>(EtbB + (size_t)bi.y * 256 + tg * 32 + 16);
    unsigned moff = ((unsigned)(tg * 32)) ^ (((unsigned)(dr & 7)) << 5);
    const char* mrow = reinterpret_cast<const char*>(sMuB) + dr * 256;
    u32x4 mwa = *reinterpret_cast<const u32x4*>(mrow + moff);
    u32x4 mwb = *reinterpret_cast<const u32x4*>(mrow + (moff ^ 16));
    float ivf[16];
#pragma unroll
    for (int j = 0; j < 4; ++j) {
      f32x4 v = *reinterpret_cast<const f32x4*>(sInv + tg * 16 + j * 4);
      ivf[4 * j] = v.x; ivf[4 * j + 1] = v.y; ivf[4 * j + 2] = v.z; ivf[4 * j + 3] = v.w;
    }
    unsigned mw[8]  = {mwa.x, mwa.y, mwa.z, mwa.w, mwb.x, mwb.y, mwb.z, mwb.w};
    unsigned ew0[8] = {e0a.x, e0a.y, e0a.z, e0a.w, e0b.x, e0b.y, e0b.z, e0b.w};
    unsigned ew1[8] = {e1a.x, e1a.y, e1a.z, e1a.w, e1b.x, e1b.y, e1b.z, e1b.w};
    float den = 0.f, pacc = 0.f;
#pragma unroll
    for (int i = 0; i < 8; ++i) {
      float ta = exp2f(bf_lo(mw[i]) * LOG2E);
      float tb = exp2f(bf_hi(mw[i]) * LOG2E);
      den += ta + tb;
      float ea = bf_lo(ew0[i]) * bf_lo(ew1[i]);
      float eb = bf_hi(ew0[i]) * bf_hi(ew1[i]);
      pacc += ta * ta * ea * ivf[2 * i] + tb * tb * eb * ivf[2 * i + 1];
    }
    den  += __shfl_xor(den, 1);  pacc += __shfl_xor(pacc, 1);
    den  += __shfl_xor(den, 2);  pacc += __shfl_xor(pacc, 2);
    den  += __shfl_xor(den, 4);  pacc += __shfl_xor(pacc, 4);
    float lr = 0.f;
    if (tg == 0)
      lr = fast_log(pacc * __builtin_amdgcn_rcpf(den * den) + 1e-6f);
    lr += __shfl_xor(lr, 8);
    lr += __shfl_xor(lr, 16);
    lr += __shfl_xor(lr, 32);
    if (l == 0) sRed[12 + wid] = lr;
  }
  __syncthreads();
  if (tid == 0) {
    float k = 0.f, s = 0.f;
#pragma unroll
    for (int i = 0; i < 12; ++i) k += sRed[i];
#pragma unroll
    for (int i = 0; i < 8; ++i) s += sRed[12 + i];
    atomicAdd(&partial[1], k);
    atomicAdd(&partial[0], s);
  }
}

__global__ void finalize_kernel(const float* __restrict__ partial, float* __restrict__ out) {
  if (threadIdx.x == 0) {
    out[0] = partial[0] / (float)B_;
    out[1] = -0.5f * partial[1] / (float)B_;
  }
}

extern "C" void kernel_launch(void* const* d_in, const int* in_sizes, int n_in,
                              void* d_out, int out_size, void* d_ws, size_t ws_size,
                              hipStream_t stream) {
  const int*   bi_idx   = (const int*)d_in[0];
  const float* biterms  = (const float*)d_in[1];
  const float* rho      = (const float*)d_in[2];
  const float* alphas_W = (const float*)d_in[3];
  const float* q1_W     = (const float*)d_in[4];
  const float* q1_b     = (const float*)d_in[5];
  const float* q2_W     = (const float*)d_in[6];
  const float* q2_b     = (const float*)d_in[7];
  const float* mu_W     = (const float*)d_in[8];
  const float* mu_b     = (const float*)d_in[9];
  const float* ls_W     = (const float*)d_in[10];
  const float* ls_b     = (const float*)d_in[11];

  char* ws = (char*)d_ws;
  unsigned short* Etb   = (unsigned short*)(ws + OFF_ETB);
  float* colsum  = (float*)(ws + OFF_COLSUM);
  float* partial = (float*)(ws + OFF_PART);
  unsigned char*  q1p8  = (unsigned char*)(ws + OFF_Q1P8);
  unsigned char*  q2p8  = (unsigned char*)(ws + OFF_Q2P8);
  unsigned char*  headp8= (unsigned char*)(ws + OFF_HEADP8);
  unsigned char*  xp8   = (unsigned char*)(ws + OFF_XP8);

  hipMemsetAsync(ws + OFF_COLSUM, 0, 1024, stream);  // colsum + partials (must precede pre_kernel atomics)

  // merged pre-kernel: 782 tb blocks + ceil(25188/8)=3149 pack blocks
  pre_kernel<<<NTB + (NPACKU + 7) / 8, 512, 0, stream>>>(
      rho, alphas_W, biterms, q1_W, q2_W, mu_W, ls_W,
      Etb, colsum, xp8, q1p8, q2p8, headp8);

  fused_kernel<<<B_ / 64, 768, 0, stream>>>(bi_idx, q1_b, q2_b, mu_b, ls_b,
                                            xp8, q1p8, q2p8, headp8, Etb, colsum, partial);

  finalize_kernel<<<1, 64, 0, stream>>>(partial, (float*)d_out);
}

// Round 17
// 397.862 us; speedup vs baseline: 5.8409x; 1.0204x over previous
//
#include <hip/hip_runtime.h>
#include <hip/hip_bf16.h>

// Problem dims
#define V_ 50000
#define E_ 300
#define H_ 800
#define K_ 128
#define B_ 131072

typedef float  f32x4 __attribute__((ext_vector_type(4)));
typedef float  f32x2 __attribute__((ext_vector_type(2)));
typedef int    i32x4 __attribute__((ext_vector_type(4)));
typedef int    i32x8 __attribute__((ext_vector_type(8)));
typedef unsigned int u32x2 __attribute__((ext_vector_type(2)));
typedef unsigned int u32x4 __attribute__((ext_vector_type(4)));
typedef __bf16 bf16x8 __attribute__((ext_vector_type(8)));

#define LOG2E 1.4426950408889634f
#define HSTR 912   // LDS h stride bytes: 16B-aligned

// ---------------- ws layout (bytes) ----------------
static constexpr size_t OFF_ETB    = 0;                                  // bf16 [50048][128]
static constexpr size_t SZ_ETB     = (size_t)50048 * 128 * 2;            // 12,812,288
static constexpr size_t OFF_COLSUM = SZ_ETB;                             // 128 f32
static constexpr size_t OFF_PART   = OFF_COLSUM + 512;                   // [0]=loss,[1]=kld
static constexpr size_t OFF_Q1P8   = OFF_COLSUM + 1024;                  // 50 strips x 3 chunks x 2KB
static constexpr size_t OFF_Q2P8   = OFF_Q1P8 + (size_t)150 * 2048;      // 50 x 7 x 2KB
static constexpr size_t OFF_HEADP8 = OFF_Q2P8 + (size_t)350 * 2048;      // 16 x 7 x 2KB (mu 0-7, ls 8-15)
static constexpr size_t OFF_XP8    = OFF_HEADP8 + (size_t)112 * 2048;    // 8192 rfg x 3 chunks x 2KB

static __device__ __forceinline__ f32x4 mfma_bf16(i32x4 a, i32x4 b, f32x4 c) {
  return __builtin_amdgcn_mfma_f32_16x16x32_bf16(
      __builtin_bit_cast(bf16x8, a), __builtin_bit_cast(bf16x8, b), c, 0, 0, 0);
}
// MX-scaled fp8xfp8, K=128, all scales = 1.0 (E8M0 0x7F in every byte)
static __device__ __forceinline__ f32x4 mfma_mx(i32x8 a, i32x8 b, f32x4 c) {
  return __builtin_amdgcn_mfma_scale_f32_16x16x128_f8f6f4(
      a, b, c, 0 /*A=fp8*/, 0 /*B=fp8*/, 0, 0x7F7F7F7F, 0, 0x7F7F7F7F);
}

static __device__ __forceinline__ unsigned int cvt_pk_bf16(float a, float b) {
  unsigned int d;
  asm volatile("v_cvt_pk_bf16_f32 %0, %1, %2" : "=v"(d) : "v"(a), "v"(b));
  return d;
}
static __device__ __forceinline__ unsigned int pk_fp8x4(float a, float b, float c, float d) {
  int w = __builtin_amdgcn_cvt_pk_fp8_f32(a, b, 0, false);
  w = __builtin_amdgcn_cvt_pk_fp8_f32(c, d, w, true);
  return (unsigned int)w;
}

// tanh(x) = 1 - 2/(exp(2x)+1); correct limits at +/-inf without clamping.
static __device__ __forceinline__ float tanh_fast(float x) {
  float e = exp2f(x * 2.8853900817779268f);  // exp(2x)
  return __builtin_fmaf(-2.f, __builtin_amdgcn_rcpf(e + 1.f), 1.f);
}
static __device__ __forceinline__ float fast_log(float x) {
  return __builtin_amdgcn_logf(x) * 0.69314718056f;
}
static __device__ __forceinline__ float bf_lo(unsigned int w) {
  return __builtin_bit_cast(float, w << 16);
}
static __device__ __forceinline__ float bf_hi(unsigned int w) {
  return __builtin_bit_cast(float, w & 0xFFFF0000u);
}
static __device__ __forceinline__ f32x4 fzero() {
  f32x4 z; z.x = 0.f; z.y = 0.f; z.z = 0.f; z.w = 0.f; return z;
}
static __device__ __forceinline__ i32x8 ld32B(const void* p) {
  i32x4 a = *reinterpret_cast<const i32x4*>(p);
  i32x4 b = *reinterpret_cast<const i32x4*>(reinterpret_cast<const char*>(p) + 16);
  return __builtin_shufflevector(a, b, 0, 1, 2, 3, 4, 5, 6, 7);
}
static __device__ __forceinline__ unsigned int pk4tanh(f32x4 a, f32x4 b4) {
  return pk_fp8x4(tanh_fast(a[0] + b4.x), tanh_fast(a[1] + b4.y),
                  tanh_fast(a[2] + b4.z), tanh_fast(a[3] + b4.w));
}

// ---------------- pack units (64-lane jobs) ----------------
static __device__ __forceinline__ void pack_x_unit(int fi, int l, const float* __restrict__ X,
                                                   unsigned char* __restrict__ dst) {
  int rfg = fi / 3, c = fi - rfg * 3;
  int row = rfg * 16 + (l & 15);
  int k0 = c * 128 + ((l >> 4) << 5);
  const float* p = X + (size_t)row * 300 + k0;
  unsigned int o[8];
  if (c < 2) {
    // fast path: k0+28 <= 252 < 300 always -> unguarded
#pragma unroll
    for (int g = 0; g < 8; ++g) {
      f32x4 v = *reinterpret_cast<const f32x4*>(p + g * 4);
      o[g] = pk_fp8x4(v.x, v.y, v.z, v.w);
    }
  } else {
#pragma unroll
    for (int g = 0; g < 8; ++g) {
      f32x4 v = fzero();
      if (k0 + g * 4 < 300) v = *reinterpret_cast<const f32x4*>(p + g * 4);
      o[g] = pk_fp8x4(v.x, v.y, v.z, v.w);
    }
  }
  *reinterpret_cast<u32x4*>(dst + (size_t)fi * 2048 + l * 32) = *reinterpret_cast<u32x4*>(&o[0]);
  *reinterpret_cast<u32x4*>(dst + (size_t)fi * 2048 + l * 32 + 16) = *reinterpret_cast<u32x4*>(&o[4]);
}
static __device__ __forceinline__ void pack_w_unit(int b, int l, const float* __restrict__ W,
                                                   int Kdim, int N, int nc,
                                                   unsigned char* __restrict__ dst) {
  int sl = b / nc, c = b - sl * nc;
  int n = sl * 16 + (l & 15);
  int k0 = c * 128 + ((l >> 4) << 5);
  unsigned int o[8];
#pragma unroll
  for (int r = 0; r < 8; ++r) {
    float t[4];
#pragma unroll
    for (int tt = 0; tt < 4; ++tt) {
      int k = k0 + r * 4 + tt;
      t[tt] = (k < Kdim) ? W[(size_t)k * N + n] : 0.f;
    }
    o[r] = pk_fp8x4(t[0], t[1], t[2], t[3]);
  }
  *reinterpret_cast<u32x4*>(dst + (size_t)b * 2048 + l * 32) = *reinterpret_cast<u32x4*>(&o[0]);
  *reinterpret_cast<u32x4*>(dst + (size_t)b * 2048 + l * 32 + 16) = *reinterpret_cast<u32x4*>(&o[4]);
}

#define NTB 782            // tb blocks (64 vocab rows each)
#define XU  (8192 * 3)     // x-frag units
#define NPACKU (XU + 612)  // + 150 q1 + 350 q2 + 56 mu + 56 ls

// ---------------- merged pre-kernel: tb (blocks 0..781) + all packing (rest) ----------------
__global__ __launch_bounds__(512) void pre_kernel(
    const float* __restrict__ rho, const float* __restrict__ alW,
    const float* __restrict__ biterms, const float* __restrict__ q1W,
    const float* __restrict__ q2W, const float* __restrict__ muW,
    const float* __restrict__ lsW,
    unsigned short* __restrict__ Etb, float* __restrict__ colsum,
    unsigned char* __restrict__ xp8, unsigned char* __restrict__ q1p8,
    unsigned char* __restrict__ q2p8, unsigned char* __restrict__ headp8) {
  const int tid = threadIdx.x;
  const int wid = tid >> 6, l = tid & 63;

  if (blockIdx.x >= NTB) {
    // ---- packing section ----
    int ub = (blockIdx.x - NTB) * 8 + wid;
    if (ub < XU) { pack_x_unit(ub, l, biterms, xp8); return; }
    int u2 = ub - XU;
    if (u2 < 150)      { pack_w_unit(u2, l, q1W, E_, H_, 3, q1p8); return; }
    else if (u2 < 500) { pack_w_unit(u2 - 150, l, q2W, H_, H_, 7, q2p8); return; }
    else if (u2 < 556) { pack_w_unit(u2 - 500, l, muW, H_, K_, 7, headp8); return; }
    else if (u2 < 612) { pack_w_unit(u2 - 556, l, lsW, H_, K_, 7, headp8 + (size_t)56 * 2048); return; }
    return;
  }

  // ---- tb section: Etb(bf16) = exp(rho @ alphas), colsum over vocab ----
  const int srow = l & 15, q = l >> 4;
  const int tile = blockIdx.x;
  const int acol = wid * 16 + srow;   // alpha column for this wave's strip

  // prefetch this wave's 10 alpha fragments inline; k>=300 zero-padded (makes rho
  // fast path safe: garbage k>=300 contributes 0)
  i32x4 awf[10];
#pragma unroll
  for (int ks = 0; ks < 9; ++ks) {
    float t[8];
#pragma unroll
    for (int j = 0; j < 8; ++j)
      t[j] = alW[(size_t)(ks * 32 + q * 8 + j) * K_ + acol];
    i32x4 o;
    o.x = (int)cvt_pk_bf16(t[0], t[1]);
    o.y = (int)cvt_pk_bf16(t[2], t[3]);
    o.z = (int)cvt_pk_bf16(t[4], t[5]);
    o.w = (int)cvt_pk_bf16(t[6], t[7]);
    awf[ks] = o;
  }
  {
    float t[8];
#pragma unroll
    for (int j = 0; j < 8; ++j) {
      int k = 288 + q * 8 + j;
      t[j] = (k < E_) ? alW[(size_t)k * K_ + acol] : 0.f;
    }
    i32x4 o;
    o.x = (int)cvt_pk_bf16(t[0], t[1]);
    o.y = (int)cvt_pk_bf16(t[2], t[3]);
    o.z = (int)cvt_pk_bf16(t[4], t[5]);
    o.w = (int)cvt_pk_bf16(t[6], t[7]);
    awf[9] = o;
  }

  f32x4 acc[4];
#pragma unroll
  for (int rf = 0; rf < 4; ++rf) acc[rf] = fzero();

  if (tile < NTB - 1) {
    // -------- fast path: no guards --------
    for (int ks = 0; ks < 10; ++ks) {
#pragma unroll
      for (int rf = 0; rf < 4; ++rf) {
        int row = tile * 64 + rf * 16 + srow;
        const float* p = rho + (size_t)row * 300 + ks * 32 + q * 8;
        f32x4 v0 = *reinterpret_cast<const f32x4*>(p);
        f32x4 v1 = *reinterpret_cast<const f32x4*>(p + 4);
        i32x4 rv;
        rv.x = (int)cvt_pk_bf16(v0.x, v0.y);
        rv.y = (int)cvt_pk_bf16(v0.z, v0.w);
        rv.z = (int)cvt_pk_bf16(v1.x, v1.y);
        rv.w = (int)cvt_pk_bf16(v1.z, v1.w);
        acc[rf] = mfma_bf16(awf[ks], rv, acc[rf]);
      }
    }
    float cs[4] = {0.f, 0.f, 0.f, 0.f};
#pragma unroll
    for (int rf = 0; rf < 4; ++rf) {
      int row = tile * 64 + rf * 16 + srow;
      float e0 = exp2f(acc[rf][0] * LOG2E);
      float e1 = exp2f(acc[rf][1] * LOG2E);
      float e2 = exp2f(acc[rf][2] * LOG2E);
      float e3 = exp2f(acc[rf][3] * LOG2E);
      u32x2 o;
      o.x = cvt_pk_bf16(e0, e1);
      o.y = cvt_pk_bf16(e2, e3);
      *reinterpret_cast<u32x2*>(Etb + (size_t)row * 128 + wid * 16 + q * 4) = o;
      cs[0] += e0; cs[1] += e1; cs[2] += e2; cs[3] += e3;
    }
#pragma unroll
    for (int d = 1; d < 16; d <<= 1) {
#pragma unroll
      for (int r = 0; r < 4; ++r) cs[r] += __shfl_xor(cs[r], d);
    }
    if (srow == 0) {
#pragma unroll
      for (int r = 0; r < 4; ++r) atomicAdd(&colsum[wid * 16 + q * 4 + r], cs[r]);
    }
    return;
  }

  // -------- guarded path (last tile only) --------
  for (int ks = 0; ks < 10; ++ks) {
#pragma unroll
    for (int rf = 0; rf < 4; ++rf) {
      int row = tile * 64 + rf * 16 + srow;
      f32x4 v0 = fzero(), v1 = fzero();
      if (row < V_) {
        const float* p = rho + (size_t)row * 300 + ks * 32 + q * 8;
        if (ks < 9) {
          v0 = *reinterpret_cast<const f32x4*>(p);
          v1 = *reinterpret_cast<const f32x4*>(p + 4);
        } else {
          if (q < 2)  v0 = *reinterpret_cast<const f32x4*>(p);
          if (q == 0) v1 = *reinterpret_cast<const f32x4*>(p + 4);
        }
      }
      i32x4 rv;
      rv.x = (int)cvt_pk_bf16(v0.x, v0.y);
      rv.y = (int)cvt_pk_bf16(v0.z, v0.w);
      rv.z = (int)cvt_pk_bf16(v1.x, v1.y);
      rv.w = (int)cvt_pk_bf16(v1.z, v1.w);
      acc[rf] = mfma_bf16(awf[ks], rv, acc[rf]);
    }
  }
  float cs[4] = {0.f, 0.f, 0.f, 0.f};
#pragma unroll
  for (int rf = 0; rf < 4; ++rf) {
    int row = tile * 64 + rf * 16 + srow;
    float e0 = exp2f(acc[rf][0] * LOG2E);
    float e1 = exp2f(acc[rf][1] * LOG2E);
    float e2 = exp2f(acc[rf][2] * LOG2E);
    float e3 = exp2f(acc[rf][3] * LOG2E);
    if (row < V_) {
      u32x2 o;
      o.x = cvt_pk_bf16(e0, e1);
      o.y = cvt_pk_bf16(e2, e3);
      *reinterpret_cast<u32x2*>(Etb + (size_t)row * 128 + wid * 16 + q * 4) = o;
      cs[0] += e0; cs[1] += e1; cs[2] += e2; cs[3] += e3;
    }
  }
#pragma unroll
  for (int d = 1; d < 16; d <<= 1) {
#pragma unroll
    for (int r = 0; r < 4; ++r) cs[r] += __shfl_xor(cs[r], d);
  }
  if (srow == 0) {
#pragma unroll
    for (int r = 0; r < 4; ++r) atomicAdd(&colsum[wid * 16 + q * 4 + r], cs[r]);
  }
}

// ---------- fused main kernel: 64 rows/block, 12 waves (768 thr), 5 strips/wave ----------
// (768,3): 3 waves/SIMD, 170-reg cap; 72 arch + 80 AGPR = 152, no spill (r11/r14/r16).
// r17 change: h2 goes to a SEPARATE LDS buffer (sH2) -> the "all h1 reads complete"
// barrier disappears (write buffer disjoint from read buffer); 5 barriers -> 4, and
// GEMM2's epilogue no longer waits for slow waves' reads. LDS 134KB (1 block/CU is
// reg-bound anyway, extra LDS free).
// Ledger: NO s_setprio (r12), NO merged-finalize fence (r13), NEVER the 128-reg cap
// (r2/r6/r15 spilled; WRITE_SIZE = tripwire), BM=64 optimal (r10/r15 analysis).
__global__ __launch_bounds__(768, 3) void fused_kernel(
    const int* __restrict__ bi_idx,
    const float* __restrict__ q1b, const float* __restrict__ q2b,
    const float* __restrict__ mub, const float* __restrict__ lsb,
    const unsigned char* __restrict__ xp8, const unsigned char* __restrict__ q1p8,
    const unsigned char* __restrict__ q2p8, const unsigned char* __restrict__ headp8,
    const unsigned short* __restrict__ Etb, const float* __restrict__ colsum,
    float* __restrict__ partial) {
  __shared__ __align__(16) unsigned char sH[64 * HSTR];   // 58,368 B (fp8 h1, 896 cols)
  __shared__ __align__(16) unsigned char sH2[64 * HSTR];  // 58,368 B (fp8 h2, 896 cols)
  __shared__ __align__(16) unsigned char sMuB[64 * 256];  // 16,384 B (bf16 mu, XOR-swizzled)
  __shared__ __align__(16) float sInv[128];
  __shared__ float sRed[20];

  const int tid = threadIdx.x, wid = tid >> 6, l = tid & 63;
  const int swid = __builtin_amdgcn_readfirstlane(wid);   // 0..11
  const int srow = l & 15, q = l >> 4;
  const unsigned loff = (unsigned)l * 32u;
  const int row0 = blockIdx.x * 64;

  if (tid < 128) { float c = colsum[tid]; sInv[tid] = 1.f / (c * c); }
  char* sHb  = reinterpret_cast<char*>(sH);
  char* sH2b = reinterpret_cast<char*>(sH2);
  // zero-fill cols 800..895 of BOTH h buffers (read by K=896 chunks, never written)
  {
    int idx = tid * 2;
    int zr = idx / 24, zc = idx - zr * 24;
    u32x2 z2; z2.x = 0u; z2.y = 0u;
    *reinterpret_cast<u32x2*>(sHb  + zr * HSTR + 800 + zc * 4) = z2;
    *reinterpret_cast<u32x2*>(sH2b + zr * HSTR + 800 + zc * 4) = z2;
  }

  f32x4 acc[5][4];

  // ---- GEMM1: h1 = tanh(x @ q1 + b1) -> sH fp8; strips s = swid + 12*si ----
#pragma unroll
  for (int si = 0; si < 5; ++si)
#pragma unroll
    for (int rf = 0; rf < 4; ++rf) acc[si][rf] = fzero();
#pragma unroll
  for (int c = 0; c < 3; ++c) {
    i32x8 x[4];
#pragma unroll
    for (int rf = 0; rf < 4; ++rf)
      x[rf] = ld32B(xp8 + ((size_t)(blockIdx.x * 4 + rf) * 3 + c) * 2048 + loff);
#pragma unroll
    for (int si = 0; si < 5; ++si) {
      int s = swid + 12 * si;
      if (s < 50) {
        i32x8 w = ld32B(q1p8 + ((size_t)s * 3 + c) * 2048 + loff);
#pragma unroll
        for (int rf = 0; rf < 4; ++rf) acc[si][rf] = mfma_mx(w, x[rf], acc[si][rf]);
      }
    }
  }
#pragma unroll
  for (int si = 0; si < 5; ++si) {
    int s = swid + 12 * si;
    if (s < 50) {
      f32x4 b4 = *reinterpret_cast<const f32x4*>(q1b + s * 16 + q * 4);
#pragma unroll
      for (int rf = 0; rf < 4; ++rf)
        *reinterpret_cast<unsigned int*>(
            sHb + (rf * 16 + srow) * HSTR + s * 16 + q * 4) = pk4tanh(acc[si][rf], b4);
    }
  }
  __syncthreads();  // h1 complete

  // ---- GEMM2: h2 = tanh(h1 @ q2 + b2) -> sH2 (disjoint buffer: NO read barrier) ----
#pragma unroll
  for (int si = 0; si < 5; ++si)
#pragma unroll
    for (int rf = 0; rf < 4; ++rf) acc[si][rf] = fzero();
#pragma unroll
  for (int c = 0; c < 7; ++c) {
    i32x8 h[4];
#pragma unroll
    for (int rf = 0; rf < 4; ++rf)
      h[rf] = ld32B(sHb + (rf * 16 + srow) * HSTR + c * 128 + q * 32);
#pragma unroll
    for (int si = 0; si < 5; ++si) {
      int s = swid + 12 * si;
      if (s < 50) {
        i32x8 w = ld32B(q2p8 + ((size_t)s * 7 + c) * 2048 + loff);
#pragma unroll
        for (int rf = 0; rf < 4; ++rf) acc[si][rf] = mfma_mx(w, h[rf], acc[si][rf]);
      }
    }
  }
#pragma unroll
  for (int si = 0; si < 5; ++si) {
    int s = swid + 12 * si;
    if (s < 50) {
      f32x4 b4 = *reinterpret_cast<const f32x4*>(q2b + s * 16 + q * 4);
#pragma unroll
      for (int rf = 0; rf < 4; ++rf)
        *reinterpret_cast<unsigned int*>(
            sH2b + (rf * 16 + srow) * HSTR + s * 16 + q * 4) = pk4tanh(acc[si][rf], b4);
    }
  }
  __syncthreads();  // h2 complete

  // ---- GEMM3: head strips s = swid + 12*j, j=0..1 (s<8: mu, 8..15: ls); kld; mu->sMuB ----
  f32x4 acc3[2][4];
#pragma unroll
  for (int j = 0; j < 2; ++j)
#pragma unroll
    for (int rf = 0; rf < 4; ++rf) acc3[j][rf] = fzero();
#pragma unroll
  for (int c = 0; c < 7; ++c) {
    i32x8 a8[4];
#pragma unroll
    for (int rf = 0; rf < 4; ++rf)
      a8[rf] = ld32B(sH2b + (rf * 16 + srow) * HSTR + c * 128 + q * 32);
#pragma unroll
    for (int j = 0; j < 2; ++j) {
      int s = swid + 12 * j;
      if (s < 16) {
        i32x8 w = ld32B(headp8 + ((size_t)s * 7 + c) * 2048 + loff);
#pragma unroll
        for (int rf = 0; rf < 4; ++rf) acc3[j][rf] = mfma_mx(w, a8[rf], acc3[j][rf]);
      }
    }
  }
  {
    float kldp = 0.f;
    unsigned swz = ((unsigned)(srow & 7)) << 5;
#pragma unroll
    for (int j = 0; j < 2; ++j) {
      int s = swid + 12 * j;
      if (s < 8) {            // mu strip s
        f32x4 mb4 = *reinterpret_cast<const f32x4*>(mub + s * 16 + q * 4);
        unsigned coff = ((unsigned)(s * 32 + q * 8)) ^ swz;
#pragma unroll
        for (int rf = 0; rf < 4; ++rf) {
          float m0 = acc3[j][rf][0] + mb4.x, m1 = acc3[j][rf][1] + mb4.y;
          float m2 = acc3[j][rf][2] + mb4.z, m3 = acc3[j][rf][3] + mb4.w;
          kldp -= m0 * m0 + m1 * m1 + m2 * m2 + m3 * m3;
          u32x2 o;
          o.x = cvt_pk_bf16(m0, m1);
          o.y = cvt_pk_bf16(m2, m3);
          *reinterpret_cast<u32x2*>(sMuB + (rf * 16 + srow) * 256 + coff) = o;
        }
      } else if (s < 16) {    // ls strip s-8
        f32x4 lb4 = *reinterpret_cast<const f32x4*>(lsb + (s - 8) * 16 + q * 4);
#pragma unroll
        for (int rf = 0; rf < 4; ++rf) {
          float v0 = acc3[j][rf][0] + lb4.x, v1 = acc3[j][rf][1] + lb4.y;
          float v2 = acc3[j][rf][2] + lb4.z, v3 = acc3[j][rf][3] + lb4.w;
          kldp += 4.f + v0 + v1 + v2 + v3
                - exp2f(v0 * LOG2E) - exp2f(v1 * LOG2E)
                - exp2f(v2 * LOG2E) - exp2f(v3 * LOG2E);
        }
      }
    }
#pragma unroll
    for (int d = 1; d < 64; d <<= 1) kldp += __shfl_xor(kldp, d);
    if (l == 0) sRed[wid] = kldp;
  }
  __syncthreads();

  // ---- decode (waves 0-7): lane = (row rg=l>>3, topic-group tg=l&7 of 16 topics) ----
  if (swid < 8) {
    const int rg = l >> 3, tg = l & 7;
    const int dr = wid * 8 + rg;   // 0..63
    int2 bi = reinterpret_cast<const int2*>(bi_idx)[row0 + dr];
    const char* EtbB = reinterpret_cast<const char*>(Etb);
    u32x4 e0a = *reinterpret_cast<const u32x4*>(EtbB + (size_t)bi.x * 256 + tg * 32);
    u32x4 e0b = *reinterpret_cast<const u32x4*>(EtbB + (size_t)bi.x * 256 + tg * 32 + 16);
    u32x4 e1a = *reinterpret_cast<const u32x4*>(EtbB + (size_t)bi.y * 256 + tg * 32);
    u32x4 e1b = *reinterpret_cast<const u32x4*>(EtbB + (size_t)bi.y * 256 + tg * 32 + 16);
    unsigned moff = ((unsigned)(tg * 32)) ^ (((unsigned)(dr & 7)) << 5);
    const char* mrow = reinterpret_cast<const char*>(sMuB) + dr * 256;
    u32x4 mwa = *reinterpret_cast<const u32x4*>(mrow + moff);
    u32x4 mwb = *reinterpret_cast<const u32x4*>(mrow + (moff ^ 16));
    float ivf[16];
#pragma unroll
    for (int j = 0; j < 4; ++j) {
      f32x4 v = *reinterpret_cast<const f32x4*>(sInv + tg * 16 + j * 4);
      ivf[4 * j] = v.x; ivf[4 * j + 1] = v.y; ivf[4 * j + 2] = v.z; ivf[4 * j + 3] = v.w;
    }
    unsigned mw[8]  = {mwa.x, mwa.y, mwa.z, mwa.w, mwb.x, mwb.y, mwb.z, mwb.w};
    unsigned ew0[8] = {e0a.x, e0a.y, e0a.z, e0a.w, e0b.x, e0b.y, e0b.z, e0b.w};
    unsigned ew1[8] = {e1a.x, e1a.y, e1a.z, e1a.w, e1b.x, e1b.y, e1b.z, e1b.w};
    float den = 0.f, pacc = 0.f;
#pragma unroll
    for (int i = 0; i < 8; ++i) {
      float ta = exp2f(bf_lo(mw[i]) * LOG2E);
      float tb = exp2f(bf_hi(mw[i]) * LOG2E);
      den += ta + tb;
      float ea = bf_lo(ew0[i]) * bf_lo(ew1[i]);
      float eb = bf_hi(ew0[i]) * bf_hi(ew1[i]);
      pacc += ta * ta * ea * ivf[2 * i] + tb * tb * eb * ivf[2 * i + 1];
    }
    den  += __shfl_xor(den, 1);  pacc += __shfl_xor(pacc, 1);
    den  += __shfl_xor(den, 2);  pacc += __shfl_xor(pacc, 2);
    den  += __shfl_xor(den, 4);  pacc += __shfl_xor(pacc, 4);
    float lr = 0.f;
    if (tg == 0)
      lr = fast_log(pacc * __builtin_amdgcn_rcpf(den * den) + 1e-6f);
    lr += __shfl_xor(lr, 8);
    lr += __shfl_xor(lr, 16);
    lr += __shfl_xor(lr, 32);
    if (l == 0) sRed[12 + wid] = lr;
  }
  __syncthreads();
  if (tid == 0) {
    float k = 0.f, s = 0.f;
#pragma unroll
    for (int i = 0; i < 12; ++i) k += sRed[i];
#pragma unroll
    for (int i = 0; i < 8; ++i) s += sRed[12 + i];
    atomicAdd(&partial[1], k);
    atomicAdd(&partial[0], s);
  }
}

__global__ void finalize_kernel(const float* __restrict__ partial, float* __restrict__ out) {
  if (threadIdx.x == 0) {
    out[0] = partial[0] / (float)B_;
    out[1] = -0.5f * partial[1] / (float)B_;
  }
}

extern "C" void kernel_launch(void* const* d_in, const int* in_sizes, int n_in,
                              void* d_out, int out_size, void* d_ws, size_t ws_size,
                              hipStream_t stream) {
  const int*   bi_idx   = (const int*)d_in[0];
  const float* biterms  = (const float*)d_in[1];
  const float* rho      = (const float*)d_in[2];
  const float* alphas_W = (const float*)d_in[3];
  const float* q1_W     = (const float*)d_in[4];
  const float* q1_b     = (const float*)d_in[5];
  const float* q2_W     = (const float*)d_in[6];
  const float* q2_b     = (const float*)d_in[7];
  const float* mu_W     = (const float*)d_in[8];
  const float* mu_b     = (const float*)d_in[9];
  const float* ls_W     = (const float*)d_in[10];
  const float* ls_b     = (const float*)d_in[11];

  char* ws = (char*)d_ws;
  unsigned short* Etb   = (unsigned short*)(ws + OFF_ETB);
  float* colsum  = (float*)(ws + OFF_COLSUM);
  float* partial = (float*)(ws + OFF_PART);
  unsigned char*  q1p8  = (unsigned char*)(ws + OFF_Q1P8);
  unsigned char*  q2p8  = (unsigned char*)(ws + OFF_Q2P8);
  unsigned char*  headp8= (unsigned char*)(ws + OFF_HEADP8);
  unsigned char*  xp8   = (unsigned char*)(ws + OFF_XP8);

  hipMemsetAsync(ws + OFF_COLSUM, 0, 1024, stream);  // colsum + partials (must precede pre_kernel atomics)

  // merged pre-kernel: 782 tb blocks + ceil(25188/8)=3149 pack blocks
  pre_kernel<<<NTB + (NPACKU + 7) / 8, 512, 0, stream>>>(
      rho, alphas_W, biterms, q1_W, q2_W, mu_W, ls_W,
      Etb, colsum, xp8, q1p8, q2p8, headp8);

  fused_kernel<<<B_ / 64, 768, 0, stream>>>(bi_idx, q1_b, q2_b, mu_b, ls_b,
                                            xp8, q1p8, q2p8, headp8, Etb, colsum, partial);

  finalize_kernel<<<1, 64, 0, stream>>>(partial, (float*)d_out);
}